// Round 4
// baseline (569.811 us; speedup 1.0000x reference)
//
#include <hip/hip_runtime.h>
#include <math.h>

#define INV_EPS  (-20.0f)                 // -1/0.05
#define QSCALE   (-20.0f / 65535.0f)      // decode (natural log domain)
#define L2E      1.44269504088896340736f
#define QS2      (-20.0f / 65535.0f * 1.44269504088896340736f)  // decode (log2 domain)
#define TOLV     0.001f
#define MAX_ITER 50
#define NBLK     256
#define NTHR     1024

// ---- workspace layout ----
#define CTRL_CNT(g)   ((g) * 64)
#define CTRL_GEN(g)   ((g) * 64 + 32)
#define CTRL_ARR(d)   (2048 + (d) * 32)
#define CTRL_CHG(d)   (3648 + (d) * 32)
#define CTRL_INTS     5248
#define Q_OFF_BYTES   (1u << 20)           // compact u16 rows 6,7 at ws+1MB (16 MB)

#define RX __ATOMIC_RELAXED
#define SC __HIP_MEMORY_SCOPE_AGENT

__device__ __forceinline__ float wave_red_sum64(float x) {
    x += __int_as_float(__builtin_amdgcn_update_dpp(0, __float_as_int(x), 0x111, 0xf, 0xf, false));
    x += __int_as_float(__builtin_amdgcn_update_dpp(0, __float_as_int(x), 0x112, 0xf, 0xf, false));
    x += __int_as_float(__builtin_amdgcn_update_dpp(0, __float_as_int(x), 0x114, 0xf, 0xf, false));
    x += __int_as_float(__builtin_amdgcn_update_dpp(0, __float_as_int(x), 0x118, 0xf, 0xf, false));
    x += __int_as_float(__builtin_amdgcn_update_dpp(0, __float_as_int(x), 0x142, 0xf, 0xf, false));
    x += __int_as_float(__builtin_amdgcn_update_dpp(0, __float_as_int(x), 0x143, 0xf, 0xf, false));
    return __int_as_float(__builtin_amdgcn_readlane(__float_as_int(x), 63));
}

// 8-block (one batch) barrier, relaxed atomics only (no L2 flush; see R2/R3).
__device__ __forceinline__ void group_sync(int* cnt, int* gen) {
    __syncthreads();
    if (threadIdx.x == 0) {
        int g = __hip_atomic_load(gen, RX, SC);
        int a = __hip_atomic_fetch_add(cnt, 1, RX, SC);
        if (a == 7) {
            __hip_atomic_store(cnt, 0, RX, SC);
            __hip_atomic_store(gen, g + 1, RX, SC);
        } else {
            while (__hip_atomic_load(gen, RX, SC) == g)
                __builtin_amdgcn_s_sleep(1);
        }
    }
    __syncthreads();
}

// decode 16 u16 from (QA,QB) in log2 domain, row-sum, u-update, col-accumulate.
// All names static -> everything stays in registers.
#define ROW_COMPUTE(QA, QB, LR)                                               \
  {                                                                           \
    float e0  = exp2f(fmaf((float)((QA).x & 0xffffu), QS2, vL00));            \
    float e1  = exp2f(fmaf((float)((QA).x >> 16),     QS2, vL01));            \
    float e2  = exp2f(fmaf((float)((QA).y & 0xffffu), QS2, vL02));            \
    float e3  = exp2f(fmaf((float)((QA).y >> 16),     QS2, vL03));            \
    float e4  = exp2f(fmaf((float)((QA).z & 0xffffu), QS2, vL04));            \
    float e5  = exp2f(fmaf((float)((QA).z >> 16),     QS2, vL05));            \
    float e6  = exp2f(fmaf((float)((QA).w & 0xffffu), QS2, vL06));            \
    float e7  = exp2f(fmaf((float)((QA).w >> 16),     QS2, vL07));            \
    float e8  = exp2f(fmaf((float)((QB).x & 0xffffu), QS2, vL08));            \
    float e9  = exp2f(fmaf((float)((QB).x >> 16),     QS2, vL09));            \
    float e10 = exp2f(fmaf((float)((QB).y & 0xffffu), QS2, vL10));            \
    float e11 = exp2f(fmaf((float)((QB).y >> 16),     QS2, vL11));            \
    float e12 = exp2f(fmaf((float)((QB).z & 0xffffu), QS2, vL12));            \
    float e13 = exp2f(fmaf((float)((QB).z >> 16),     QS2, vL13));            \
    float e14 = exp2f(fmaf((float)((QB).w & 0xffffu), QS2, vL14));            \
    float e15 = exp2f(fmaf((float)((QB).w >> 16),     QS2, vL15));            \
    float s = (((e0+e1)+(e2+e3))+((e4+e5)+(e6+e7)))                           \
            + (((e8+e9)+(e10+e11))+((e12+e13)+(e14+e15)));                    \
    s = wave_red_sum64(s);                                                    \
    float u_new = lg_src[LR] - __logf(s);                                     \
    flag |= (fabsf(u_new - u_ring[pv][LR]) >= TOLV);                          \
    if (lane == 0) u_ring[cur][LR] = u_new;                                   \
    float eu = __expf(u_new);                                                 \
    cs0  = fmaf(e0,  eu, cs0);  cs1  = fmaf(e1,  eu, cs1);                    \
    cs2  = fmaf(e2,  eu, cs2);  cs3  = fmaf(e3,  eu, cs3);                    \
    cs4  = fmaf(e4,  eu, cs4);  cs5  = fmaf(e5,  eu, cs5);                    \
    cs6  = fmaf(e6,  eu, cs6);  cs7  = fmaf(e7,  eu, cs7);                    \
    cs8  = fmaf(e8,  eu, cs8);  cs9  = fmaf(e9,  eu, cs9);                    \
    cs10 = fmaf(e10, eu, cs10); cs11 = fmaf(e11, eu, cs11);                   \
    cs12 = fmaf(e12, eu, cs12); cs13 = fmaf(e13, eu, cs13);                   \
    cs14 = fmaf(e14, eu, cs14); cs15 = fmaf(e15, eu, cs15);                   \
  }

// it0: fp32 row -> quantize u16 (rint, same as R3) -> stash -> compute from q
#define IT0_ROW(i, STASH)                                                     \
  {                                                                           \
    const float* rp = cbase + ((size_t)(i) << 10);                            \
    float4 a0 = *(const float4*)(rp);                                         \
    float4 a1 = *(const float4*)(rp + 256);                                   \
    float4 a2 = *(const float4*)(rp + 512);                                   \
    float4 a3 = *(const float4*)(rp + 768);                                   \
    uint4 w0, w1;                                                             \
    w0.x = (uint)rintf(a0.x*65535.f) | ((uint)rintf(a0.y*65535.f) << 16);     \
    w0.y = (uint)rintf(a0.z*65535.f) | ((uint)rintf(a0.w*65535.f) << 16);     \
    w0.z = (uint)rintf(a1.x*65535.f) | ((uint)rintf(a1.y*65535.f) << 16);     \
    w0.w = (uint)rintf(a1.z*65535.f) | ((uint)rintf(a1.w*65535.f) << 16);     \
    w1.x = (uint)rintf(a2.x*65535.f) | ((uint)rintf(a2.y*65535.f) << 16);     \
    w1.y = (uint)rintf(a2.z*65535.f) | ((uint)rintf(a2.w*65535.f) << 16);     \
    w1.z = (uint)rintf(a3.x*65535.f) | ((uint)rintf(a3.y*65535.f) << 16);     \
    w1.w = (uint)rintf(a3.z*65535.f) | ((uint)rintf(a3.w*65535.f) << 16);     \
    STASH;                                                                    \
    ROW_COMPUTE(w0, w1, (widx << 3) + (i));                                   \
  }

// epilogue: one row, 4 column-chunks, coalesced float4 stores
#define EPI_ROW(QA, QB, i)                                                    \
  {                                                                           \
    const float uu = u_ring[slot][(widx << 3) + (i)];                         \
    float* op = out + (((size_t)(rowb + (widx << 3) + (i))) << 10) + (lane << 2); \
    float4 vv, o;                                                             \
    vv = *(const float4*)&v_ring[slot][lane << 2];                            \
    o.x = exp2f(fmaf((float)((QA).x & 0xffffu), QS2, (uu + vv.x) * L2E));     \
    o.y = exp2f(fmaf((float)((QA).x >> 16),     QS2, (uu + vv.y) * L2E));     \
    o.z = exp2f(fmaf((float)((QA).y & 0xffffu), QS2, (uu + vv.z) * L2E));     \
    o.w = exp2f(fmaf((float)((QA).y >> 16),     QS2, (uu + vv.w) * L2E));     \
    *(float4*)(op) = o;                                                       \
    vv = *(const float4*)&v_ring[slot][256 + (lane << 2)];                    \
    o.x = exp2f(fmaf((float)((QA).z & 0xffffu), QS2, (uu + vv.x) * L2E));     \
    o.y = exp2f(fmaf((float)((QA).z >> 16),     QS2, (uu + vv.y) * L2E));     \
    o.z = exp2f(fmaf((float)((QA).w & 0xffffu), QS2, (uu + vv.z) * L2E));     \
    o.w = exp2f(fmaf((float)((QA).w >> 16),     QS2, (uu + vv.w) * L2E));     \
    *(float4*)(op + 256) = o;                                                 \
    vv = *(const float4*)&v_ring[slot][512 + (lane << 2)];                    \
    o.x = exp2f(fmaf((float)((QB).x & 0xffffu), QS2, (uu + vv.x) * L2E));     \
    o.y = exp2f(fmaf((float)((QB).x >> 16),     QS2, (uu + vv.y) * L2E));     \
    o.z = exp2f(fmaf((float)((QB).y & 0xffffu), QS2, (uu + vv.z) * L2E));     \
    o.w = exp2f(fmaf((float)((QB).y >> 16),     QS2, (uu + vv.w) * L2E));     \
    *(float4*)(op + 512) = o;                                                 \
    vv = *(const float4*)&v_ring[slot][768 + (lane << 2)];                    \
    o.x = exp2f(fmaf((float)((QB).z & 0xffffu), QS2, (uu + vv.x) * L2E));     \
    o.y = exp2f(fmaf((float)((QB).z >> 16),     QS2, (uu + vv.y) * L2E));     \
    o.z = exp2f(fmaf((float)((QB).w & 0xffffu), QS2, (uu + vv.z) * L2E));     \
    o.w = exp2f(fmaf((float)((QB).w >> 16),     QS2, (uu + vv.w) * L2E));     \
    *(float4*)(op + 768) = o;                                                 \
  }

// LDS q index: rows 4,5 (r=0,1), chunk p, per wave/lane
#define LQ(r, p) (((((widx << 1) | (r)) << 1) | (p)) * 64 + lane)

// QM=1: cost resident on-chip after it0 — rows 0-3 in VGPRs, 4-5 in LDS,
//       6-7 streamed from a compact 16MB qbuf (L2-resident: 2MB/XCD).
// QM=0: exact R3 fp32-streaming fallback (ws too small).
template<int QM>
__global__ __launch_bounds__(NTHR, 4) void sinkhorn_fused(
    const float* __restrict__ cost, const float* __restrict__ src,
    const float* __restrict__ tgt, float* __restrict__ out,
    int* __restrict__ ctrl, uint* __restrict__ qbuf)
{
    const int t    = threadIdx.x;
    const int lane = t & 63;
    const int widx = t >> 6;
    const int rx   = blockIdx.x & 7;
    const int sx   = blockIdx.x >> 3;
    const int grp  = rx * 4 + (sx >> 3);    // batch id, 0..31
    const int j    = sx & 7;                // 128-row slab within batch

    __shared__ float smS[16][64][17];
    __shared__ float v_ring[4][1024];
    __shared__ float u_ring[4][128];
    __shared__ float lg_tgt[1024];
    __shared__ float lg_src[128];
    __shared__ uint4 qlds[QM == 1 ? 16 * 2 * 2 * 64 : 1];   // 64 KB (rows 4,5)
    __shared__ int   s_chg, s_stop;

    int* cnt = ctrl + CTRL_CNT(grp);
    int* gen = ctrl + CTRL_GEN(grp);

    const int rowb = (grp << 10) + (j << 7);
    const float* cbase = cost + ((size_t)(rowb + (widx << 3)) << 10) + (lane << 2);
    // compact stream buffer for rows 6,7 of each 8-row group
    uint4* qs4 = nullptr;
    if constexpr (QM == 1)
        qs4 = (uint4*)qbuf + (((size_t)((rowb >> 3) + widx)) << 8) + lane;
    float* const Pg = out + ((size_t)grp << 20);   // group scratch in own out-slab

    lg_tgt[t] = __logf(tgt[(grp << 10) + t] + 1e-12f);
    if (t < 128) {
        lg_src[t]    = __logf(src[rowb + t] + 1e-12f);
        u_ring[3][t] = 0.f;
    }
    v_ring[3][t] = 0.f;

    // persistent q registers, rows 0-3 (QM=1)
    uint4 q0a, q0b, q1a, q1b, q2a, q2b, q3a, q3b;

    // QM=0 persistent fp32 prefetch
    float4 f0, f1, f2, f3, g0, g1, g2, g3;
    if constexpr (QM == 0) {
        f0 = *(const float4*)(cbase);
        f1 = *(const float4*)(cbase + 256);
        f2 = *(const float4*)(cbase + 512);
        f3 = *(const float4*)(cbase + 768);
        const float* r1p = cbase + ((size_t)1 << 10);
        g0 = *(const float4*)(r1p);
        g1 = *(const float4*)(r1p + 256);
        g2 = *(const float4*)(r1p + 512);
        g3 = *(const float4*)(r1p + 768);
    }

    __syncthreads();

    int K = -1;
    for (int it = 0; it < MAX_ITER; ++it) {
        const int cur = it & 3, pv = (it + 3) & 3;

        // gate on global decision for it-2 (slack-2 pipeline; see R1-R3)
        if (t == 0) {
            int stop = 0;
            if (it >= 2) {
                const int d = it - 2;
                while (__hip_atomic_load(ctrl + CTRL_ARR(d), RX, SC) != NBLK)
                    __builtin_amdgcn_s_sleep(1);
                stop = (__hip_atomic_load(ctrl + CTRL_CHG(d), RX, SC) == 0);
            }
            s_stop = stop;
            s_chg  = 0;
        }
        __syncthreads();
        if (s_stop) { K = it - 2; break; }

        const float* vp = &v_ring[pv][lane << 2];
        float4 vo0 = *(const float4*)(vp);
        float4 vo1 = *(const float4*)(vp + 256);
        float4 vo2 = *(const float4*)(vp + 512);
        float4 vo3 = *(const float4*)(vp + 768);

        bool flag = false;

        if constexpr (QM == 1) {
            // log2-domain v_old
            const float vL00 = vo0.x*L2E, vL01 = vo0.y*L2E, vL02 = vo0.z*L2E, vL03 = vo0.w*L2E;
            const float vL04 = vo1.x*L2E, vL05 = vo1.y*L2E, vL06 = vo1.z*L2E, vL07 = vo1.w*L2E;
            const float vL08 = vo2.x*L2E, vL09 = vo2.y*L2E, vL10 = vo2.z*L2E, vL11 = vo2.w*L2E;
            const float vL12 = vo3.x*L2E, vL13 = vo3.y*L2E, vL14 = vo3.z*L2E, vL15 = vo3.w*L2E;
            float cs0=0,cs1=0,cs2=0,cs3=0,cs4=0,cs5=0,cs6=0,cs7=0,
                  cs8=0,cs9=0,cs10=0,cs11=0,cs12=0,cs13=0,cs14=0,cs15=0;

            if (it == 0) {
                IT0_ROW(0, { q0a = w0; q0b = w1; })
                IT0_ROW(1, { q1a = w0; q1b = w1; })
                IT0_ROW(2, { q2a = w0; q2b = w1; })
                IT0_ROW(3, { q3a = w0; q3b = w1; })
                IT0_ROW(4, { qlds[LQ(0,0)] = w0; qlds[LQ(0,1)] = w1; })
                IT0_ROW(5, { qlds[LQ(1,0)] = w0; qlds[LQ(1,1)] = w1; })
                IT0_ROW(6, { qs4[0]   = w0; qs4[64]  = w1; })
                IT0_ROW(7, { qs4[128] = w0; qs4[192] = w1; })
            } else {
                // stream rows 6,7 early (L2 hit; hides under rows 0-5 compute)
                uint4 s6a = qs4[0], s6b = qs4[64], s7a = qs4[128], s7b = qs4[192];
                ROW_COMPUTE(q0a, q0b, (widx << 3) + 0)
                ROW_COMPUTE(q1a, q1b, (widx << 3) + 1)
                uint4 l4a = qlds[LQ(0,0)], l4b = qlds[LQ(0,1)];
                ROW_COMPUTE(q2a, q2b, (widx << 3) + 2)
                uint4 l5a = qlds[LQ(1,0)], l5b = qlds[LQ(1,1)];
                ROW_COMPUTE(q3a, q3b, (widx << 3) + 3)
                ROW_COMPUTE(l4a, l4b, (widx << 3) + 4)
                ROW_COMPUTE(l5a, l5b, (widx << 3) + 5)
                ROW_COMPUTE(s6a, s6b, (widx << 3) + 6)
                ROW_COMPUTE(s7a, s7b, (widx << 3) + 7)
            }

            smS[widx][lane][0]  = cs0;  smS[widx][lane][1]  = cs1;
            smS[widx][lane][2]  = cs2;  smS[widx][lane][3]  = cs3;
            smS[widx][lane][4]  = cs4;  smS[widx][lane][5]  = cs5;
            smS[widx][lane][6]  = cs6;  smS[widx][lane][7]  = cs7;
            smS[widx][lane][8]  = cs8;  smS[widx][lane][9]  = cs9;
            smS[widx][lane][10] = cs10; smS[widx][lane][11] = cs11;
            smS[widx][lane][12] = cs12; smS[widx][lane][13] = cs13;
            smS[widx][lane][14] = cs14; smS[widx][lane][15] = cs15;
        } else {
            float cs[16];
            #pragma unroll
            for (int s = 0; s < 16; ++s) cs[s] = 0.f;
            #pragma unroll 1
            for (int i = 0; i < 8; ++i) {
                const float* nxt = cbase + ((size_t)((i + 2) & 7) << 10);
                float4 p0 = *(const float4*)(nxt);
                float4 p1 = *(const float4*)(nxt + 256);
                float4 p2 = *(const float4*)(nxt + 512);
                float4 p3 = *(const float4*)(nxt + 768);
                float e[16];
                e[ 0] = __expf(fmaf(f0.x, INV_EPS, vo0.x));
                e[ 1] = __expf(fmaf(f0.y, INV_EPS, vo0.y));
                e[ 2] = __expf(fmaf(f0.z, INV_EPS, vo0.z));
                e[ 3] = __expf(fmaf(f0.w, INV_EPS, vo0.w));
                e[ 4] = __expf(fmaf(f1.x, INV_EPS, vo1.x));
                e[ 5] = __expf(fmaf(f1.y, INV_EPS, vo1.y));
                e[ 6] = __expf(fmaf(f1.z, INV_EPS, vo1.z));
                e[ 7] = __expf(fmaf(f1.w, INV_EPS, vo1.w));
                e[ 8] = __expf(fmaf(f2.x, INV_EPS, vo2.x));
                e[ 9] = __expf(fmaf(f2.y, INV_EPS, vo2.y));
                e[10] = __expf(fmaf(f2.z, INV_EPS, vo2.z));
                e[11] = __expf(fmaf(f2.w, INV_EPS, vo2.w));
                e[12] = __expf(fmaf(f3.x, INV_EPS, vo3.x));
                e[13] = __expf(fmaf(f3.y, INV_EPS, vo3.y));
                e[14] = __expf(fmaf(f3.z, INV_EPS, vo3.z));
                e[15] = __expf(fmaf(f3.w, INV_EPS, vo3.w));
                float s01 = e[0]+e[1],   s23 = e[2]+e[3];
                float s45 = e[4]+e[5],   s67 = e[6]+e[7];
                float s89 = e[8]+e[9],   sab = e[10]+e[11];
                float scd = e[12]+e[13], sef = e[14]+e[15];
                float s = ((s01+s23)+(s45+s67)) + ((s89+sab)+(scd+sef));
                s = wave_red_sum64(s);
                const int lr = (widx << 3) + i;
                float u_new = lg_src[lr] - __logf(s);
                flag |= (fabsf(u_new - u_ring[pv][lr]) >= TOLV);
                if (lane == 0) u_ring[cur][lr] = u_new;
                float eu = __expf(u_new);
                #pragma unroll
                for (int k = 0; k < 16; ++k)
                    cs[k] = fmaf(e[k], eu, cs[k]);
                f0 = g0; f1 = g1; f2 = g2; f3 = g3;
                g0 = p0; g1 = p1; g2 = p2; g3 = p3;
            }
            #pragma unroll
            for (int s = 0; s < 16; ++s) smS[widx][lane][s] = cs[s];
        }

        if (lane == 0 && flag) s_chg = 1;
        __syncthreads();

        // publish: chg-or IC-complete before arrival add
        if (t == 0) {
            if (s_chg)
                __hip_atomic_fetch_or(ctrl + CTRL_CHG(it), 1, RX, SC);
            asm volatile("s_waitcnt vmcnt(0)" ::: "memory");
            __hip_atomic_fetch_add(ctrl + CTRL_ARR(it), 1, RX, SC);
        }

        // block partial for column t
        float* Pb = Pg + (size_t)(((it & 1) << 3) + j) * 1040;
        {
            const int L  = (t >> 2) & 63;
            const int sl = ((t >> 8) << 2) | (t & 3);
            float S = 0.f;
            #pragma unroll
            for (int w = 0; w < 16; ++w) S += smS[w][L][sl];
            float hcol = __expf(-v_ring[pv][t]);
            __hip_atomic_store(Pb + t, S * hcol, RX, SC);
        }

        group_sync(cnt, gen);

        // redundant v-combine (bitwise-identical across the 8 blocks)
        {
            float* Pf = Pg + (size_t)((it & 1) << 3) * 1040;
            float S = 0.f;
            #pragma unroll
            for (int jj = 0; jj < 8; ++jj)
                S += __hip_atomic_load(Pf + jj * 1040 + t, RX, SC);
            v_ring[cur][t] = lg_tgt[t] - __logf(S);
        }
        __syncthreads();
    }

    if (K < 0) {
        if (t == 0) {
            while (__hip_atomic_load(ctrl + CTRL_ARR(48), RX, SC) != NBLK)
                __builtin_amdgcn_s_sleep(1);
            s_stop = (__hip_atomic_load(ctrl + CTRL_CHG(48), RX, SC) == 0);
        }
        __syncthreads();
        K = s_stop ? 48 : 49;
    }

    // reload streamed rows for epilogue before quiescing group scratch
    uint4 s6a, s6b, s7a, s7b;
    if constexpr (QM == 1) {
        s6a = qs4[0]; s6b = qs4[64]; s7a = qs4[128]; s7b = qs4[192];
    }

    group_sync(cnt, gen);   // siblings done reading partials

    {
        const int slot = K & 3;
        if constexpr (QM == 1) {
            EPI_ROW(q0a, q0b, 0)
            EPI_ROW(q1a, q1b, 1)
            EPI_ROW(q2a, q2b, 2)
            EPI_ROW(q3a, q3b, 3)
            { uint4 l4a = qlds[LQ(0,0)], l4b = qlds[LQ(0,1)]; EPI_ROW(l4a, l4b, 4) }
            { uint4 l5a = qlds[LQ(1,0)], l5b = qlds[LQ(1,1)]; EPI_ROW(l5a, l5b, 5) }
            EPI_ROW(s6a, s6b, 6)
            EPI_ROW(s7a, s7b, 7)
        } else {
            const size_t base = ((size_t)rowb) << 10;
            #pragma unroll 1
            for (int i = 0; i < 32; ++i) {
                const int g4  = (i << 10) + t;
                const int lr  = g4 >> 8;
                const int c4  = (g4 & 255) << 2;
                const size_t e = base + ((size_t)g4 << 2);
                float4 cc = *(const float4*)(cost + e);
                float4 vv = *(const float4*)&v_ring[slot][c4];
                const float uu = u_ring[slot][lr];
                float4 o;
                o.x = __expf(fmaf(cc.x, INV_EPS, uu + vv.x));
                o.y = __expf(fmaf(cc.y, INV_EPS, uu + vv.y));
                o.z = __expf(fmaf(cc.z, INV_EPS, uu + vv.z));
                o.w = __expf(fmaf(cc.w, INV_EPS, uu + vv.w));
                *(float4*)(out + e) = o;
            }
        }
    }
}

extern "C" void kernel_launch(void* const* d_in, const int* in_sizes, int n_in,
                              void* d_out, int out_size, void* d_ws, size_t ws_size,
                              hipStream_t stream) {
    const float* cost = (const float*)d_in[0];
    const float* src  = (const float*)d_in[1];
    const float* tgt  = (const float*)d_in[2];
    float* out = (float*)d_out;
    int*   ctrl = (int*)d_ws;
    (void)in_sizes; (void)n_in; (void)out_size;

    hipMemsetAsync(d_ws, 0, CTRL_INTS * sizeof(int), stream);

    const size_t need = (size_t)Q_OFF_BYTES + ((size_t)16 << 20);
    if (ws_size >= need) {
        uint* qbuf = (uint*)((char*)d_ws + Q_OFF_BYTES);
        sinkhorn_fused<1><<<dim3(NBLK), dim3(NTHR), 0, stream>>>(
            cost, src, tgt, out, ctrl, qbuf);
    } else {
        sinkhorn_fused<0><<<dim3(NBLK), dim3(NTHR), 0, stream>>>(
            cost, src, tgt, out, ctrl, nullptr);
    }
}

// Round 5
// 401.209 us; speedup vs baseline: 1.4202x; 1.4202x over previous
//
#include <hip/hip_runtime.h>
#include <math.h>

#define INV_EPS  (-20.0f)                 // -1/0.05
#define QINV     (1.0f / 65535.0f)
#define LN65535  11.090354888959125f
#define TOLV     0.001f
#define MAX_ITER 50
#define NBLK     256
#define NTHR     1024

// ---- workspace layout ----
#define CTRL_CNT(g)   ((g) * 64)
#define CTRL_GEN(g)   ((g) * 64 + 32)
#define CTRL_ARR(d)   (2048 + (d) * 32)
#define CTRL_CHG(d)   (3648 + (d) * 32)
#define CTRL_INTS     5248
#define Q_OFF_BYTES   (1u << 20)           // u16 E-matrix at ws+1MB (64 MB)

#define RX __ATOMIC_RELAXED
#define SC __HIP_MEMORY_SCOPE_AGENT

typedef float f32x4 __attribute__((ext_vector_type(4)));
typedef uint  u32x4 __attribute__((ext_vector_type(4)));
typedef uint  u32x2 __attribute__((ext_vector_type(2)));

__device__ __forceinline__ float wave_red_sum64(float x) {
    x += __int_as_float(__builtin_amdgcn_update_dpp(0, __float_as_int(x), 0x111, 0xf, 0xf, false));
    x += __int_as_float(__builtin_amdgcn_update_dpp(0, __float_as_int(x), 0x112, 0xf, 0xf, false));
    x += __int_as_float(__builtin_amdgcn_update_dpp(0, __float_as_int(x), 0x114, 0xf, 0xf, false));
    x += __int_as_float(__builtin_amdgcn_update_dpp(0, __float_as_int(x), 0x118, 0xf, 0xf, false));
    x += __int_as_float(__builtin_amdgcn_update_dpp(0, __float_as_int(x), 0x142, 0xf, 0xf, false));
    x += __int_as_float(__builtin_amdgcn_update_dpp(0, __float_as_int(x), 0x143, 0xf, 0xf, false));
    return __int_as_float(__builtin_amdgcn_readlane(__float_as_int(x), 63));
}

// 8-block (one batch) barrier, relaxed atomics only (no L2 flush; see R2/R3).
__device__ __forceinline__ void group_sync(int* cnt, int* gen) {
    __syncthreads();
    if (threadIdx.x == 0) {
        int g = __hip_atomic_load(gen, RX, SC);
        int a = __hip_atomic_fetch_add(cnt, 1, RX, SC);
        if (a == 7) {
            __hip_atomic_store(cnt, 0, RX, SC);
            __hip_atomic_store(gen, g + 1, RX, SC);
        } else {
            while (__hip_atomic_load(gen, RX, SC) == g)
                __builtin_amdgcn_s_sleep(1);
        }
    }
    __syncthreads();
}

// Linear-E row math: row-sum via 4 fma chains (s = sum qf*evs), u update,
// col accumulate cs += qf*eu. All names static -> registers.
#define ROWMATH(LR)                                                            \
  {                                                                            \
    float sA = fmaf(qf0, evs0, fmaf(qf4, evs4, fmaf(qf8,  evs8,  qf12*evs12)));\
    float sB = fmaf(qf1, evs1, fmaf(qf5, evs5, fmaf(qf9,  evs9,  qf13*evs13)));\
    float sC = fmaf(qf2, evs2, fmaf(qf6, evs6, fmaf(qf10, evs10, qf14*evs14)));\
    float sD = fmaf(qf3, evs3, fmaf(qf7, evs7, fmaf(qf11, evs11, qf15*evs15)));\
    float s = (sA + sB) + (sC + sD);                                           \
    s = wave_red_sum64(s);                                                     \
    float u_new = lg_src[LR] - __logf(s);                                      \
    flag |= (fabsf(u_new - u_ring[pv][LR]) >= TOLV);                           \
    if (lane == 0) u_ring[cur][LR] = u_new;                                    \
    float eu = __expf(u_new);                                                  \
    cs0 = fmaf(qf0, eu, cs0);  cs1 = fmaf(qf1, eu, cs1);                       \
    cs2 = fmaf(qf2, eu, cs2);  cs3 = fmaf(qf3, eu, cs3);                       \
    cs4 = fmaf(qf4, eu, cs4);  cs5 = fmaf(qf5, eu, cs5);                       \
    cs6 = fmaf(qf6, eu, cs6);  cs7 = fmaf(qf7, eu, cs7);                       \
    cs8 = fmaf(qf8, eu, cs8);  cs9 = fmaf(qf9, eu, cs9);                       \
    cs10 = fmaf(qf10, eu, cs10); cs11 = fmaf(qf11, eu, cs11);                  \
    cs12 = fmaf(qf12, eu, cs12); cs13 = fmaf(qf13, eu, cs13);                  \
    cs14 = fmaf(qf14, eu, cs14); cs15 = fmaf(qf15, eu, cs15);                  \
  }

#define ROW_LIN(QA, QB, LR)                                                    \
  {                                                                            \
    float qf0  = (float)((QA).x & 0xffffu), qf1  = (float)((QA).x >> 16),      \
          qf2  = (float)((QA).y & 0xffffu), qf3  = (float)((QA).y >> 16),      \
          qf4  = (float)((QA).z & 0xffffu), qf5  = (float)((QA).z >> 16),      \
          qf6  = (float)((QA).w & 0xffffu), qf7  = (float)((QA).w >> 16),      \
          qf8  = (float)((QB).x & 0xffffu), qf9  = (float)((QB).x >> 16),      \
          qf10 = (float)((QB).y & 0xffffu), qf11 = (float)((QB).y >> 16),      \
          qf12 = (float)((QB).z & 0xffffu), qf13 = (float)((QB).z >> 16),      \
          qf14 = (float)((QB).w & 0xffffu), qf15 = (float)((QB).w >> 16);      \
    ROWMATH(LR)                                                                \
  }

#define NTL(p)  __builtin_nontemporal_load(p)

// QM=1: E = exp(-20C) quantized u16 linear. it0 builds qbuf from fp32 cost;
//       iters 1+ stream qbuf: rows 0-2 of each 8-row group via normal loads
//       (24 MB = 3 MB/XCD -> L2-resident), rows 3-7 non-temporal (IC stream,
//       no L2 pollution). No per-element exp in the steady loop or epilogue.
// QM=0: exact R3 fp32-streaming fallback (ws too small).
template<int QM>
__global__ __launch_bounds__(NTHR, 2) void sinkhorn_fused(
    const float* __restrict__ cost, const float* __restrict__ src,
    const float* __restrict__ tgt, float* __restrict__ out,
    int* __restrict__ ctrl, uint* __restrict__ qbuf)
{
    const int t    = threadIdx.x;
    const int lane = t & 63;
    const int widx = t >> 6;
    const int rx   = blockIdx.x & 7;
    const int sx   = blockIdx.x >> 3;
    const int grp  = rx * 4 + (sx >> 3);    // batch id, 0..31
    const int j    = sx & 7;                // 128-row slab within batch

    __shared__ float smS[16][64][17];
    __shared__ float v_ring[4][1024];
    __shared__ float u_ring[4][128];
    __shared__ float lg_tgt[1024];
    __shared__ float lg_src[128];
    __shared__ int   s_chg, s_stop;

    int* cnt = ctrl + CTRL_CNT(grp);
    int* gen = ctrl + CTRL_GEN(grp);

    const int rowb = (grp << 10) + (j << 7);
    const float* cbase = cost + ((size_t)(rowb + (widx << 3)) << 10) + (lane << 2);
    // q layout (R3-proven): row r = uint4 [r*128, r*128+128); this thread's
    // slice of row (r8+i) at qb4[i*128 + {0,64}]
    u32x4* qb4 = nullptr;
    const u32x4* qb4c = nullptr;
    if constexpr (QM == 1) {
        qb4  = (u32x4*)qbuf + (size_t)(rowb + (widx << 3)) * 128 + lane;
        qb4c = qb4;
    }
    float* const Pg = out + ((size_t)grp << 20);   // group scratch in own out-slab

    // lg_tgt pre-shifted by ln(65535): v = log c - log(S/65535)
    lg_tgt[t] = __logf(tgt[(grp << 10) + t] + 1e-12f) + ((QM == 1) ? LN65535 : 0.f);
    if (t < 128) {
        lg_src[t]    = __logf(src[rowb + t] + 1e-12f);
        u_ring[3][t] = 0.f;
    }
    v_ring[3][t] = 0.f;

    // QM=0 persistent fp32 prefetch
    float4 f0, f1, f2, f3, g0, g1, g2, g3;
    if constexpr (QM == 0) {
        f0 = *(const float4*)(cbase);
        f1 = *(const float4*)(cbase + 256);
        f2 = *(const float4*)(cbase + 512);
        f3 = *(const float4*)(cbase + 768);
        const float* r1p = cbase + ((size_t)1 << 10);
        g0 = *(const float4*)(r1p);
        g1 = *(const float4*)(r1p + 256);
        g2 = *(const float4*)(r1p + 512);
        g3 = *(const float4*)(r1p + 768);
    }

    __syncthreads();

    int K = -1;
    for (int it = 0; it < MAX_ITER; ++it) {
        const int cur = it & 3, pv = (it + 3) & 3;

        // gate on global decision for it-2 (slack-2 pipeline; see R1-R3)
        if (t == 0) {
            int stop = 0;
            if (it >= 2) {
                const int d = it - 2;
                while (__hip_atomic_load(ctrl + CTRL_ARR(d), RX, SC) != NBLK)
                    __builtin_amdgcn_s_sleep(1);
                stop = (__hip_atomic_load(ctrl + CTRL_CHG(d), RX, SC) == 0);
            }
            s_stop = stop;
            s_chg  = 0;
        }
        __syncthreads();
        if (s_stop) { K = it - 2; break; }

        bool flag = false;

        if constexpr (QM == 1) {
            const int r8 = widx << 3;
            // evs[k] = exp(v_old[col_k]) / 65535 (scale folded here)
            const float* vp = &v_ring[pv][lane << 2];
            f32x4 va = *(const f32x4*)vp;
            f32x4 vb = *(const f32x4*)(vp + 256);
            f32x4 vc = *(const f32x4*)(vp + 512);
            f32x4 vd = *(const f32x4*)(vp + 768);
            const float evs0  = __expf(va.x)*QINV, evs1  = __expf(va.y)*QINV,
                        evs2  = __expf(va.z)*QINV, evs3  = __expf(va.w)*QINV,
                        evs4  = __expf(vb.x)*QINV, evs5  = __expf(vb.y)*QINV,
                        evs6  = __expf(vb.z)*QINV, evs7  = __expf(vb.w)*QINV,
                        evs8  = __expf(vc.x)*QINV, evs9  = __expf(vc.y)*QINV,
                        evs10 = __expf(vc.z)*QINV, evs11 = __expf(vc.w)*QINV,
                        evs12 = __expf(vd.x)*QINV, evs13 = __expf(vd.y)*QINV,
                        evs14 = __expf(vd.z)*QINV, evs15 = __expf(vd.w)*QINV;
            float cs0=0,cs1=0,cs2=0,cs3=0,cs4=0,cs5=0,cs6=0,cs7=0,
                  cs8=0,cs9=0,cs10=0,cs11=0,cs12=0,cs13=0,cs14=0,cs15=0;

            if (it == 0) {
                // fp32 cost (nt stream) -> E -> quantize -> store -> compute
                const f32x4* cb4 = (const f32x4*)cbase;
                f32x4 a0=NTL(cb4),     a1=NTL(cb4+64),  a2=NTL(cb4+128), a3=NTL(cb4+192);
                f32x4 b0=NTL(cb4+256), b1=NTL(cb4+320), b2=NTL(cb4+384), b3=NTL(cb4+448);
                #pragma unroll 1
                for (int i = 0; i < 8; ++i) {
                    const f32x4* nx = cb4 + (size_t)((i + 2) & 7) * 256;
                    f32x4 p0=NTL(nx), p1=NTL(nx+64), p2=NTL(nx+128), p3=NTL(nx+192);
                    float qf0  = rintf(__expf(a0.x*INV_EPS)*65535.f);
                    float qf1  = rintf(__expf(a0.y*INV_EPS)*65535.f);
                    float qf2  = rintf(__expf(a0.z*INV_EPS)*65535.f);
                    float qf3  = rintf(__expf(a0.w*INV_EPS)*65535.f);
                    float qf4  = rintf(__expf(a1.x*INV_EPS)*65535.f);
                    float qf5  = rintf(__expf(a1.y*INV_EPS)*65535.f);
                    float qf6  = rintf(__expf(a1.z*INV_EPS)*65535.f);
                    float qf7  = rintf(__expf(a1.w*INV_EPS)*65535.f);
                    float qf8  = rintf(__expf(a2.x*INV_EPS)*65535.f);
                    float qf9  = rintf(__expf(a2.y*INV_EPS)*65535.f);
                    float qf10 = rintf(__expf(a2.z*INV_EPS)*65535.f);
                    float qf11 = rintf(__expf(a2.w*INV_EPS)*65535.f);
                    float qf12 = rintf(__expf(a3.x*INV_EPS)*65535.f);
                    float qf13 = rintf(__expf(a3.y*INV_EPS)*65535.f);
                    float qf14 = rintf(__expf(a3.z*INV_EPS)*65535.f);
                    float qf15 = rintf(__expf(a3.w*INV_EPS)*65535.f);
                    u32x4 w0, w1;
                    w0.x = (uint)qf0  | ((uint)qf1  << 16);
                    w0.y = (uint)qf2  | ((uint)qf3  << 16);
                    w0.z = (uint)qf4  | ((uint)qf5  << 16);
                    w0.w = (uint)qf6  | ((uint)qf7  << 16);
                    w1.x = (uint)qf8  | ((uint)qf9  << 16);
                    w1.y = (uint)qf10 | ((uint)qf11 << 16);
                    w1.z = (uint)qf12 | ((uint)qf13 << 16);
                    w1.w = (uint)qf14 | ((uint)qf15 << 16);
                    u32x4* dst = qb4 + i * 128;
                    if (i < 3) { dst[0] = w0; dst[64] = w1; }           // L2-resident rows
                    else { __builtin_nontemporal_store(w0, dst);
                           __builtin_nontemporal_store(w1, dst + 64); } // streamed rows
                    ROWMATH(r8 + i)
                    a0=b0; a1=b1; a2=b2; a3=b3;
                    b0=p0; b1=p1; b2=p2; b3=p3;
                }
            } else {
                // rows 0-2 normal (L2-hit), rows 3-7 non-temporal (IC stream);
                // depth-1 prefetch, A/B pair rotation (16 regs in flight)
                u32x4 A0 = qb4c[0],   A1 = qb4c[64];
                u32x4 B0 = qb4c[128], B1 = qb4c[192];
                ROW_LIN(A0, A1, r8+0)  A0 = qb4c[256];     A1 = qb4c[320];
                ROW_LIN(B0, B1, r8+1)  B0 = NTL(qb4c+384); B1 = NTL(qb4c+448);
                ROW_LIN(A0, A1, r8+2)  A0 = NTL(qb4c+512); A1 = NTL(qb4c+576);
                ROW_LIN(B0, B1, r8+3)  B0 = NTL(qb4c+640); B1 = NTL(qb4c+704);
                ROW_LIN(A0, A1, r8+4)  A0 = NTL(qb4c+768); A1 = NTL(qb4c+832);
                ROW_LIN(B0, B1, r8+5)  B0 = NTL(qb4c+896); B1 = NTL(qb4c+960);
                ROW_LIN(A0, A1, r8+6)
                ROW_LIN(B0, B1, r8+7)
            }

            smS[widx][lane][0]  = cs0;  smS[widx][lane][1]  = cs1;
            smS[widx][lane][2]  = cs2;  smS[widx][lane][3]  = cs3;
            smS[widx][lane][4]  = cs4;  smS[widx][lane][5]  = cs5;
            smS[widx][lane][6]  = cs6;  smS[widx][lane][7]  = cs7;
            smS[widx][lane][8]  = cs8;  smS[widx][lane][9]  = cs9;
            smS[widx][lane][10] = cs10; smS[widx][lane][11] = cs11;
            smS[widx][lane][12] = cs12; smS[widx][lane][13] = cs13;
            smS[widx][lane][14] = cs14; smS[widx][lane][15] = cs15;
        } else {
            const float* vp = &v_ring[pv][lane << 2];
            float4 vo0 = *(const float4*)(vp);
            float4 vo1 = *(const float4*)(vp + 256);
            float4 vo2 = *(const float4*)(vp + 512);
            float4 vo3 = *(const float4*)(vp + 768);
            float cs[16];
            #pragma unroll
            for (int s = 0; s < 16; ++s) cs[s] = 0.f;
            #pragma unroll 1
            for (int i = 0; i < 8; ++i) {
                const float* nxt = cbase + ((size_t)((i + 2) & 7) << 10);
                float4 p0 = *(const float4*)(nxt);
                float4 p1 = *(const float4*)(nxt + 256);
                float4 p2 = *(const float4*)(nxt + 512);
                float4 p3 = *(const float4*)(nxt + 768);
                float e[16];
                e[ 0] = __expf(fmaf(f0.x, INV_EPS, vo0.x));
                e[ 1] = __expf(fmaf(f0.y, INV_EPS, vo0.y));
                e[ 2] = __expf(fmaf(f0.z, INV_EPS, vo0.z));
                e[ 3] = __expf(fmaf(f0.w, INV_EPS, vo0.w));
                e[ 4] = __expf(fmaf(f1.x, INV_EPS, vo1.x));
                e[ 5] = __expf(fmaf(f1.y, INV_EPS, vo1.y));
                e[ 6] = __expf(fmaf(f1.z, INV_EPS, vo1.z));
                e[ 7] = __expf(fmaf(f1.w, INV_EPS, vo1.w));
                e[ 8] = __expf(fmaf(f2.x, INV_EPS, vo2.x));
                e[ 9] = __expf(fmaf(f2.y, INV_EPS, vo2.y));
                e[10] = __expf(fmaf(f2.z, INV_EPS, vo2.z));
                e[11] = __expf(fmaf(f2.w, INV_EPS, vo2.w));
                e[12] = __expf(fmaf(f3.x, INV_EPS, vo3.x));
                e[13] = __expf(fmaf(f3.y, INV_EPS, vo3.y));
                e[14] = __expf(fmaf(f3.z, INV_EPS, vo3.z));
                e[15] = __expf(fmaf(f3.w, INV_EPS, vo3.w));
                float s01 = e[0]+e[1],   s23 = e[2]+e[3];
                float s45 = e[4]+e[5],   s67 = e[6]+e[7];
                float s89 = e[8]+e[9],   sab = e[10]+e[11];
                float scd = e[12]+e[13], sef = e[14]+e[15];
                float s = ((s01+s23)+(s45+s67)) + ((s89+sab)+(scd+sef));
                s = wave_red_sum64(s);
                const int lr = (widx << 3) + i;
                float u_new = lg_src[lr] - __logf(s);
                flag |= (fabsf(u_new - u_ring[pv][lr]) >= TOLV);
                if (lane == 0) u_ring[cur][lr] = u_new;
                float eu = __expf(u_new);
                #pragma unroll
                for (int k = 0; k < 16; ++k)
                    cs[k] = fmaf(e[k], eu, cs[k]);
                f0 = g0; f1 = g1; f2 = g2; f3 = g3;
                g0 = p0; g1 = p1; g2 = p2; g3 = p3;
            }
            #pragma unroll
            for (int s = 0; s < 16; ++s) smS[widx][lane][s] = cs[s];
        }

        if (lane == 0 && flag) s_chg = 1;
        __syncthreads();

        // publish: chg-or IC-complete before arrival add
        if (t == 0) {
            if (s_chg)
                __hip_atomic_fetch_or(ctrl + CTRL_CHG(it), 1, RX, SC);
            asm volatile("s_waitcnt vmcnt(0)" ::: "memory");
            __hip_atomic_fetch_add(ctrl + CTRL_ARR(it), 1, RX, SC);
        }

        // block partial for column t (QM=1: raw sum; scale folded into lg_tgt)
        float* Pb = Pg + (size_t)(((it & 1) << 3) + j) * 1040;
        {
            const int L  = (t >> 2) & 63;
            const int sl = ((t >> 8) << 2) | (t & 3);
            float S = 0.f;
            #pragma unroll
            for (int w = 0; w < 16; ++w) S += smS[w][L][sl];
            if constexpr (QM == 0) S *= __expf(-v_ring[pv][t]);
            __hip_atomic_store(Pb + t, S, RX, SC);
        }

        group_sync(cnt, gen);

        // redundant v-combine (bitwise-identical across the 8 blocks)
        {
            float* Pf = Pg + (size_t)((it & 1) << 3) * 1040;
            float S = 0.f;
            #pragma unroll
            for (int jj = 0; jj < 8; ++jj)
                S += __hip_atomic_load(Pf + jj * 1040 + t, RX, SC);
            v_ring[cur][t] = lg_tgt[t] - __logf(S);
        }
        __syncthreads();
    }

    if (K < 0) {
        if (t == 0) {
            while (__hip_atomic_load(ctrl + CTRL_ARR(48), RX, SC) != NBLK)
                __builtin_amdgcn_s_sleep(1);
            s_stop = (__hip_atomic_load(ctrl + CTRL_CHG(48), RX, SC) == 0);
        }
        __syncthreads();
        K = s_stop ? 48 : 49;
    }

    group_sync(cnt, gen);   // siblings done reading partials

    {
        const int slot = K & 3;
        const size_t base = ((size_t)rowb) << 10;
        if constexpr (QM == 1) {
            // out = qf * (eu * ev/65535): no exp per element.
            // reuse lg_tgt LDS as evS (last lg_tgt use was the final v-combine)
            lg_tgt[t] = __expf(v_ring[slot][t]) * QINV;
            __syncthreads();
            const u32x2* q2 = (const u32x2*)qbuf;
            #pragma unroll 1
            for (int i = 0; i < 32; ++i) {
                const int g4  = (i << 10) + t;
                const int lr  = g4 >> 8;
                const int m0  = (g4 & 255) << 2;
                const int c   = m0 >> 8;
                const int ln  = (m0 >> 2) & 63;
                const size_t u4i = (size_t)(((rowb + lr) << 1) + (c >> 1)) * 64 + ln;
                u32x2 w = NTL(q2 + (u4i << 1) + (c & 1));
                f32x4 ev4 = *(const f32x4*)&lg_tgt[m0];
                const float uu = __expf(u_ring[slot][lr]);
                f32x4 o;
                o.x = (float)(w.x & 0xffffu) * (uu * ev4.x);
                o.y = (float)(w.x >> 16)     * (uu * ev4.y);
                o.z = (float)(w.y & 0xffffu) * (uu * ev4.z);
                o.w = (float)(w.y >> 16)     * (uu * ev4.w);
                __builtin_nontemporal_store(o, (f32x4*)(out + base + ((size_t)g4 << 2)));
            }
        } else {
            #pragma unroll 1
            for (int i = 0; i < 32; ++i) {
                const int g4  = (i << 10) + t;
                const int lr  = g4 >> 8;
                const int c4  = (g4 & 255) << 2;
                const size_t e = base + ((size_t)g4 << 2);
                float4 cc = *(const float4*)(cost + e);
                float4 vv = *(const float4*)&v_ring[slot][c4];
                const float uu = u_ring[slot][lr];
                float4 o;
                o.x = __expf(fmaf(cc.x, INV_EPS, uu + vv.x));
                o.y = __expf(fmaf(cc.y, INV_EPS, uu + vv.y));
                o.z = __expf(fmaf(cc.z, INV_EPS, uu + vv.z));
                o.w = __expf(fmaf(cc.w, INV_EPS, uu + vv.w));
                *(float4*)(out + e) = o;
            }
        }
    }
}

extern "C" void kernel_launch(void* const* d_in, const int* in_sizes, int n_in,
                              void* d_out, int out_size, void* d_ws, size_t ws_size,
                              hipStream_t stream) {
    const float* cost = (const float*)d_in[0];
    const float* src  = (const float*)d_in[1];
    const float* tgt  = (const float*)d_in[2];
    float* out = (float*)d_out;
    int*   ctrl = (int*)d_ws;
    (void)in_sizes; (void)n_in; (void)out_size;

    hipMemsetAsync(d_ws, 0, CTRL_INTS * sizeof(int), stream);

    const size_t need = (size_t)Q_OFF_BYTES + ((size_t)64 << 20);
    if (ws_size >= need) {
        uint* qbuf = (uint*)((char*)d_ws + Q_OFF_BYTES);
        sinkhorn_fused<1><<<dim3(NBLK), dim3(NTHR), 0, stream>>>(
            cost, src, tgt, out, ctrl, qbuf);
    } else {
        sinkhorn_fused<0><<<dim3(NBLK), dim3(NTHR), 0, stream>>>(
            cost, src, tgt, out, ctrl, nullptr);
    }
}

// Round 6
// 309.564 us; speedup vs baseline: 1.8407x; 1.2960x over previous
//
#include <hip/hip_runtime.h>
#include <math.h>

#define INV_EPS  (-20.0f)                 // -1/0.05
#define QINV     (1.0f / 65535.0f)
#define LN65535  11.090354888959125f
#define TOLV     0.001f
#define MAX_ITER 50
#define NBLK     256
#define NTHR     1024

// ---- workspace layout ----
#define CTRL_CNT(g)   ((g) * 64)
#define CTRL_GEN(g)   ((g) * 64 + 32)
#define CTRL_ARR(d)   (2048 + (d) * 32)
#define CTRL_CHG(d)   (3648 + (d) * 32)
#define CTRL_INTS     5248
#define Q_OFF_BYTES   (1u << 20)           // u16 E-matrix at ws+1MB (64 MB)

#define RX __ATOMIC_RELAXED
#define SC __HIP_MEMORY_SCOPE_AGENT

__device__ __forceinline__ float wave_red_sum64(float x) {
    x += __int_as_float(__builtin_amdgcn_update_dpp(0, __float_as_int(x), 0x111, 0xf, 0xf, false));
    x += __int_as_float(__builtin_amdgcn_update_dpp(0, __float_as_int(x), 0x112, 0xf, 0xf, false));
    x += __int_as_float(__builtin_amdgcn_update_dpp(0, __float_as_int(x), 0x114, 0xf, 0xf, false));
    x += __int_as_float(__builtin_amdgcn_update_dpp(0, __float_as_int(x), 0x118, 0xf, 0xf, false));
    x += __int_as_float(__builtin_amdgcn_update_dpp(0, __float_as_int(x), 0x142, 0xf, 0xf, false));
    x += __int_as_float(__builtin_amdgcn_update_dpp(0, __float_as_int(x), 0x143, 0xf, 0xf, false));
    return __int_as_float(__builtin_amdgcn_readlane(__float_as_int(x), 63));
}

// 8-block (one batch) barrier, relaxed atomics only (no acq/rel => no L2
// writeback/invalidate => XCD L2 + IC stay warm; proven R2-R5).
__device__ __forceinline__ void group_sync(int* cnt, int* gen) {
    __syncthreads();
    if (threadIdx.x == 0) {
        int g = __hip_atomic_load(gen, RX, SC);
        int a = __hip_atomic_fetch_add(cnt, 1, RX, SC);
        if (a == 7) {
            __hip_atomic_store(cnt, 0, RX, SC);
            __hip_atomic_store(gen, g + 1, RX, SC);
        } else {
            while (__hip_atomic_load(gen, RX, SC) == g)
                __builtin_amdgcn_s_sleep(1);
        }
    }
    __syncthreads();
}

// Linear-E row math: row sum s = sum q*evs (4 fma chains + wave reduce),
// u update, col accumulate cs += q*eu. All names static -> registers.
#define ROWMATH(LR)                                                            \
  {                                                                            \
    float sA = fmaf(qf0, evs0, fmaf(qf4, evs4, fmaf(qf8,  evs8,  qf12*evs12)));\
    float sB = fmaf(qf1, evs1, fmaf(qf5, evs5, fmaf(qf9,  evs9,  qf13*evs13)));\
    float sC = fmaf(qf2, evs2, fmaf(qf6, evs6, fmaf(qf10, evs10, qf14*evs14)));\
    float sD = fmaf(qf3, evs3, fmaf(qf7, evs7, fmaf(qf11, evs11, qf15*evs15)));\
    float s = (sA + sB) + (sC + sD);                                           \
    s = wave_red_sum64(s);                                                     \
    float u_new = lg_src[LR] - __logf(s);                                      \
    flag |= (fabsf(u_new - u_ring[pv][LR]) >= TOLV);                           \
    if (lane == 0) u_ring[cur][LR] = u_new;                                    \
    float eu = __expf(u_new);                                                  \
    cs0 = fmaf(qf0, eu, cs0);   cs1 = fmaf(qf1, eu, cs1);                      \
    cs2 = fmaf(qf2, eu, cs2);   cs3 = fmaf(qf3, eu, cs3);                      \
    cs4 = fmaf(qf4, eu, cs4);   cs5 = fmaf(qf5, eu, cs5);                      \
    cs6 = fmaf(qf6, eu, cs6);   cs7 = fmaf(qf7, eu, cs7);                      \
    cs8 = fmaf(qf8, eu, cs8);   cs9 = fmaf(qf9, eu, cs9);                      \
    cs10 = fmaf(qf10, eu, cs10); cs11 = fmaf(qf11, eu, cs11);                  \
    cs12 = fmaf(qf12, eu, cs12); cs13 = fmaf(qf13, eu, cs13);                  \
    cs14 = fmaf(qf14, eu, cs14); cs15 = fmaf(qf15, eu, cs15);                  \
  }

#define ROW_LIN(QA, QB, LR)                                                    \
  {                                                                            \
    float qf0  = (float)((QA).x & 0xffffu), qf1  = (float)((QA).x >> 16),      \
          qf2  = (float)((QA).y & 0xffffu), qf3  = (float)((QA).y >> 16),      \
          qf4  = (float)((QA).z & 0xffffu), qf5  = (float)((QA).z >> 16),      \
          qf6  = (float)((QA).w & 0xffffu), qf7  = (float)((QA).w >> 16),      \
          qf8  = (float)((QB).x & 0xffffu), qf9  = (float)((QB).x >> 16),      \
          qf10 = (float)((QB).y & 0xffffu), qf11 = (float)((QB).y >> 16),      \
          qf12 = (float)((QB).z & 0xffffu), qf13 = (float)((QB).z >> 16),      \
          qf14 = (float)((QB).w & 0xffffu), qf15 = (float)((QB).w >> 16);      \
    ROWMATH(LR)                                                                \
  }

// QM=1: E = exp(-20C) quantized u16 LINEAR (q = rint(E*65535)). it0 builds
//       qbuf from fp32 cost and computes from quantized values (self-
//       consistent); iters 1+ and epilogue stream qbuf (64 MB, IC-resident,
//       normal cached loads -- nt hints regressed in R5, reverted). No
//       per-element exp anywhere in the steady loop or epilogue.
// QM=0: exact R3 fp32-streaming fallback (ws too small).
template<int QM>
__global__ __launch_bounds__(NTHR, 4) void sinkhorn_fused(
    const float* __restrict__ cost, const float* __restrict__ src,
    const float* __restrict__ tgt, float* __restrict__ out,
    int* __restrict__ ctrl, uint* __restrict__ qbuf)
{
    const int t    = threadIdx.x;
    const int lane = t & 63;
    const int widx = t >> 6;
    const int rx   = blockIdx.x & 7;
    const int sx   = blockIdx.x >> 3;
    const int grp  = rx * 4 + (sx >> 3);    // batch id, 0..31
    const int j    = sx & 7;                // 128-row slab within batch

    __shared__ float smS[16][64][17];
    __shared__ float v_ring[4][1024];
    __shared__ float u_ring[4][128];
    __shared__ float lg_tgt[1024];
    __shared__ float lg_src[128];
    __shared__ int   s_chg, s_stop;

    int* cnt = ctrl + CTRL_CNT(grp);
    int* gen = ctrl + CTRL_GEN(grp);

    const int rowb = (grp << 10) + (j << 7);
    const float* cbase = cost + ((size_t)(rowb + (widx << 3)) << 10) + (lane << 2);
    // q layout (R3-proven): row r occupies uint4 [r*128, r*128+128); this
    // thread's slice of row i at qb4[i*128 + {0,64}] (8 cols per uint4:
    // first covers v-chunks 0,1; second covers chunks 2,3)
    uint4* qb4 = nullptr;
    if constexpr (QM == 1)
        qb4 = (uint4*)qbuf + (size_t)(rowb + (widx << 3)) * 128 + lane;
    float* const Pg = out + ((size_t)grp << 20);   // group scratch in own out-slab

    // lg_tgt pre-shifted by ln(65535): v = (log c + ln65535) - log(S_raw)
    lg_tgt[t] = __logf(tgt[(grp << 10) + t] + 1e-12f) + ((QM == 1) ? LN65535 : 0.f);
    if (t < 128) {
        lg_src[t]    = __logf(src[rowb + t] + 1e-12f);
        u_ring[3][t] = 0.f;
    }
    v_ring[3][t] = 0.f;

    // QM=0 persistent fp32 prefetch (rows 0,1 live across iterations)
    float4 f0, f1, f2, f3, g0, g1, g2, g3;
    if constexpr (QM == 0) {
        f0 = *(const float4*)(cbase);
        f1 = *(const float4*)(cbase + 256);
        f2 = *(const float4*)(cbase + 512);
        f3 = *(const float4*)(cbase + 768);
        const float* r1p = cbase + ((size_t)1 << 10);
        g0 = *(const float4*)(r1p);
        g1 = *(const float4*)(r1p + 256);
        g2 = *(const float4*)(r1p + 512);
        g3 = *(const float4*)(r1p + 768);
    }
    uint4 uf0 = {}, uf1 = {}, ug0 = {}, ug1 = {};   // u16 carry (QM=1, it>=1)

    __syncthreads();

    int K = -1;
    for (int it = 0; it < MAX_ITER; ++it) {
        const int cur = it & 3, pv = (it + 3) & 3;

        // gate on global decision for it-2 (slack-2 pipeline; proven R1-R5)
        if (t == 0) {
            int stop = 0;
            if (it >= 2) {
                const int d = it - 2;
                while (__hip_atomic_load(ctrl + CTRL_ARR(d), RX, SC) != NBLK)
                    __builtin_amdgcn_s_sleep(1);
                stop = (__hip_atomic_load(ctrl + CTRL_CHG(d), RX, SC) == 0);
            }
            s_stop = stop;
            s_chg  = 0;
        }
        __syncthreads();
        if (s_stop) { K = it - 2; break; }   // ring slot (it-2)&3 still live

        bool flag = false;

        if constexpr (QM == 1) {
            const int r8 = widx << 3;
            // evs[k] = exp(v_old[col_k]) / 65535 (scale folded in)
            const float* vp = &v_ring[pv][lane << 2];
            float4 va = *(const float4*)vp;
            float4 vb = *(const float4*)(vp + 256);
            float4 vc = *(const float4*)(vp + 512);
            float4 vd = *(const float4*)(vp + 768);
            const float evs0  = __expf(va.x)*QINV, evs1  = __expf(va.y)*QINV,
                        evs2  = __expf(va.z)*QINV, evs3  = __expf(va.w)*QINV,
                        evs4  = __expf(vb.x)*QINV, evs5  = __expf(vb.y)*QINV,
                        evs6  = __expf(vb.z)*QINV, evs7  = __expf(vb.w)*QINV,
                        evs8  = __expf(vc.x)*QINV, evs9  = __expf(vc.y)*QINV,
                        evs10 = __expf(vc.z)*QINV, evs11 = __expf(vc.w)*QINV,
                        evs12 = __expf(vd.x)*QINV, evs13 = __expf(vd.y)*QINV,
                        evs14 = __expf(vd.z)*QINV, evs15 = __expf(vd.w)*QINV;
            float cs0=0,cs1=0,cs2=0,cs3=0,cs4=0,cs5=0,cs6=0,cs7=0,
                  cs8=0,cs9=0,cs10=0,cs11=0,cs12=0,cs13=0,cs14=0,cs15=0;

            if (it == 0) {
                // fp32 cost -> E -> quantize -> store (cached) -> compute
                float4 a0 = *(const float4*)(cbase);
                float4 a1 = *(const float4*)(cbase + 256);
                float4 a2 = *(const float4*)(cbase + 512);
                float4 a3 = *(const float4*)(cbase + 768);
                const float* r1p = cbase + ((size_t)1 << 10);
                float4 b0 = *(const float4*)(r1p);
                float4 b1 = *(const float4*)(r1p + 256);
                float4 b2 = *(const float4*)(r1p + 512);
                float4 b3 = *(const float4*)(r1p + 768);
                #pragma unroll 1
                for (int i = 0; i < 8; ++i) {
                    const float* nxt = cbase + ((size_t)((i + 2) & 7) << 10);
                    float4 p0 = *(const float4*)(nxt);
                    float4 p1 = *(const float4*)(nxt + 256);
                    float4 p2 = *(const float4*)(nxt + 512);
                    float4 p3 = *(const float4*)(nxt + 768);

                    float qf0  = rintf(__expf(a0.x*INV_EPS)*65535.f);
                    float qf1  = rintf(__expf(a0.y*INV_EPS)*65535.f);
                    float qf2  = rintf(__expf(a0.z*INV_EPS)*65535.f);
                    float qf3  = rintf(__expf(a0.w*INV_EPS)*65535.f);
                    float qf4  = rintf(__expf(a1.x*INV_EPS)*65535.f);
                    float qf5  = rintf(__expf(a1.y*INV_EPS)*65535.f);
                    float qf6  = rintf(__expf(a1.z*INV_EPS)*65535.f);
                    float qf7  = rintf(__expf(a1.w*INV_EPS)*65535.f);
                    float qf8  = rintf(__expf(a2.x*INV_EPS)*65535.f);
                    float qf9  = rintf(__expf(a2.y*INV_EPS)*65535.f);
                    float qf10 = rintf(__expf(a2.z*INV_EPS)*65535.f);
                    float qf11 = rintf(__expf(a2.w*INV_EPS)*65535.f);
                    float qf12 = rintf(__expf(a3.x*INV_EPS)*65535.f);
                    float qf13 = rintf(__expf(a3.y*INV_EPS)*65535.f);
                    float qf14 = rintf(__expf(a3.z*INV_EPS)*65535.f);
                    float qf15 = rintf(__expf(a3.w*INV_EPS)*65535.f);
                    uint4 w0, w1;
                    w0.x = (uint)qf0  | ((uint)qf1  << 16);
                    w0.y = (uint)qf2  | ((uint)qf3  << 16);
                    w0.z = (uint)qf4  | ((uint)qf5  << 16);
                    w0.w = (uint)qf6  | ((uint)qf7  << 16);
                    w1.x = (uint)qf8  | ((uint)qf9  << 16);
                    w1.y = (uint)qf10 | ((uint)qf11 << 16);
                    w1.z = (uint)qf12 | ((uint)qf13 << 16);
                    w1.w = (uint)qf14 | ((uint)qf15 << 16);
                    qb4[(i << 7)]      = w0;
                    qb4[(i << 7) + 64] = w1;

                    ROWMATH(r8 + i)

                    a0 = b0; a1 = b1; a2 = b2; a3 = b3;
                    b0 = p0; b1 = p1; b2 = p2; b3 = p3;
                }
            } else {
                // u16 steady pass: depth-2 prefetch carried across iterations
                // (wrap rows 0,1 at i=6,7 ARE next iteration's preload)
                #pragma unroll 1
                for (int i = 0; i < 8; ++i) {
                    const int nx = ((i + 2) & 7) << 7;
                    uint4 up0 = qb4[nx];
                    uint4 up1 = qb4[nx + 64];
                    ROW_LIN(uf0, uf1, r8 + i)
                    uf0 = ug0; uf1 = ug1; ug0 = up0; ug1 = up1;
                }
            }

            smS[widx][lane][0]  = cs0;  smS[widx][lane][1]  = cs1;
            smS[widx][lane][2]  = cs2;  smS[widx][lane][3]  = cs3;
            smS[widx][lane][4]  = cs4;  smS[widx][lane][5]  = cs5;
            smS[widx][lane][6]  = cs6;  smS[widx][lane][7]  = cs7;
            smS[widx][lane][8]  = cs8;  smS[widx][lane][9]  = cs9;
            smS[widx][lane][10] = cs10; smS[widx][lane][11] = cs11;
            smS[widx][lane][12] = cs12; smS[widx][lane][13] = cs13;
            smS[widx][lane][14] = cs14; smS[widx][lane][15] = cs15;
        } else {
            const float* vp = &v_ring[pv][lane << 2];
            float4 vo0 = *(const float4*)(vp);
            float4 vo1 = *(const float4*)(vp + 256);
            float4 vo2 = *(const float4*)(vp + 512);
            float4 vo3 = *(const float4*)(vp + 768);
            float cs[16];
            #pragma unroll
            for (int s = 0; s < 16; ++s) cs[s] = 0.f;
            #pragma unroll 1
            for (int i = 0; i < 8; ++i) {
                const float* nxt = cbase + ((size_t)((i + 2) & 7) << 10);
                float4 p0 = *(const float4*)(nxt);
                float4 p1 = *(const float4*)(nxt + 256);
                float4 p2 = *(const float4*)(nxt + 512);
                float4 p3 = *(const float4*)(nxt + 768);
                float e[16];
                e[ 0] = __expf(fmaf(f0.x, INV_EPS, vo0.x));
                e[ 1] = __expf(fmaf(f0.y, INV_EPS, vo0.y));
                e[ 2] = __expf(fmaf(f0.z, INV_EPS, vo0.z));
                e[ 3] = __expf(fmaf(f0.w, INV_EPS, vo0.w));
                e[ 4] = __expf(fmaf(f1.x, INV_EPS, vo1.x));
                e[ 5] = __expf(fmaf(f1.y, INV_EPS, vo1.y));
                e[ 6] = __expf(fmaf(f1.z, INV_EPS, vo1.z));
                e[ 7] = __expf(fmaf(f1.w, INV_EPS, vo1.w));
                e[ 8] = __expf(fmaf(f2.x, INV_EPS, vo2.x));
                e[ 9] = __expf(fmaf(f2.y, INV_EPS, vo2.y));
                e[10] = __expf(fmaf(f2.z, INV_EPS, vo2.z));
                e[11] = __expf(fmaf(f2.w, INV_EPS, vo2.w));
                e[12] = __expf(fmaf(f3.x, INV_EPS, vo3.x));
                e[13] = __expf(fmaf(f3.y, INV_EPS, vo3.y));
                e[14] = __expf(fmaf(f3.z, INV_EPS, vo3.z));
                e[15] = __expf(fmaf(f3.w, INV_EPS, vo3.w));
                float s01 = e[0]+e[1],   s23 = e[2]+e[3];
                float s45 = e[4]+e[5],   s67 = e[6]+e[7];
                float s89 = e[8]+e[9],   sab = e[10]+e[11];
                float scd = e[12]+e[13], sef = e[14]+e[15];
                float s = ((s01+s23)+(s45+s67)) + ((s89+sab)+(scd+sef));
                s = wave_red_sum64(s);
                const int lr = (widx << 3) + i;
                float u_new = lg_src[lr] - __logf(s);
                flag |= (fabsf(u_new - u_ring[pv][lr]) >= TOLV);
                if (lane == 0) u_ring[cur][lr] = u_new;
                float eu = __expf(u_new);
                #pragma unroll
                for (int k = 0; k < 16; ++k)
                    cs[k] = fmaf(e[k], eu, cs[k]);
                f0 = g0; f1 = g1; f2 = g2; f3 = g3;
                g0 = p0; g1 = p1; g2 = p2; g3 = p3;
            }
            #pragma unroll
            for (int s = 0; s < 16; ++s) smS[widx][lane][s] = cs[s];
        }

        if (lane == 0 && flag) s_chg = 1;
        __syncthreads();   // also drains vmcnt: it0's q-stores are L2-visible

        // preload u16 rows 0,1 for iteration 1 (latency hides under combine)
        if (QM == 1 && it == 0) {
            uf0 = qb4[0];   uf1 = qb4[64];
            ug0 = qb4[128]; ug1 = qb4[192];
        }

        // publish: chg-or IC-complete before arrival add
        if (t == 0) {
            if (s_chg)
                __hip_atomic_fetch_or(ctrl + CTRL_CHG(it), 1, RX, SC);
            asm volatile("s_waitcnt vmcnt(0)" ::: "memory");
            __hip_atomic_fetch_add(ctrl + CTRL_ARR(it), 1, RX, SC);
        }

        // block partial for column t (QM=1: raw sum, no h fold needed --
        // cs is already pure sum q*eu)
        float* Pb = Pg + (size_t)(((it & 1) << 3) + j) * 1040;
        {
            const int L  = (t >> 2) & 63;
            const int sl = ((t >> 8) << 2) | (t & 3);
            float S = 0.f;
            #pragma unroll
            for (int w = 0; w < 16; ++w) S += smS[w][L][sl];
            if constexpr (QM == 0) S *= __expf(-v_ring[pv][t]);
            __hip_atomic_store(Pb + t, S, RX, SC);
        }

        group_sync(cnt, gen);   // all 8 slabs' partials IC-visible

        // redundant v-combine (bitwise-identical across the 8 blocks)
        {
            float* Pf = Pg + (size_t)((it & 1) << 3) * 1040;
            float S = 0.f;
            #pragma unroll
            for (int jj = 0; jj < 8; ++jj)
                S += __hip_atomic_load(Pf + jj * 1040 + t, RX, SC);
            v_ring[cur][t] = lg_tgt[t] - __logf(S);
        }
        __syncthreads();
    }

    if (K < 0) {   // ran to 50: only d=48 undecided
        if (t == 0) {
            while (__hip_atomic_load(ctrl + CTRL_ARR(48), RX, SC) != NBLK)
                __builtin_amdgcn_s_sleep(1);
            s_stop = (__hip_atomic_load(ctrl + CTRL_CHG(48), RX, SC) == 0);
        }
        __syncthreads();
        K = s_stop ? 48 : 49;
    }

    group_sync(cnt, gen);   // siblings done reading partials

    {
        const int slot = K & 3;
        const size_t base = ((size_t)rowb) << 10;
        if constexpr (QM == 1) {
            // out = q * (eu * ev/65535): no per-element exp.
            // reuse lg_tgt LDS as evS (its last use was the final v-combine)
            lg_tgt[t] = __expf(v_ring[slot][t]) * QINV;
            __syncthreads();
            const uint2* q2 = (const uint2*)qbuf;
            #pragma unroll 1
            for (int i = 0; i < 32; ++i) {
                const int g4  = (i << 10) + t;
                const int lr  = g4 >> 8;
                const int m0  = (g4 & 255) << 2;
                const int c   = m0 >> 8;
                const int ln  = (m0 >> 2) & 63;
                const size_t u4i = (size_t)(((rowb + lr) << 1) + (c >> 1)) * 64 + ln;
                uint2 w = q2[(u4i << 1) + (c & 1)];
                float4 ev4 = *(const float4*)&lg_tgt[m0];
                const float uu = __expf(u_ring[slot][lr]);
                float4 o;
                o.x = (float)(w.x & 0xffffu) * (uu * ev4.x);
                o.y = (float)(w.x >> 16)     * (uu * ev4.y);
                o.z = (float)(w.y & 0xffffu) * (uu * ev4.z);
                o.w = (float)(w.y >> 16)     * (uu * ev4.w);
                *(float4*)(out + base + ((size_t)g4 << 2)) = o;
            }
        } else {
            #pragma unroll 1
            for (int i = 0; i < 32; ++i) {
                const int g4  = (i << 10) + t;
                const int lr  = g4 >> 8;
                const int c4  = (g4 & 255) << 2;
                const size_t e = base + ((size_t)g4 << 2);
                float4 cc = *(const float4*)(cost + e);
                float4 vv = *(const float4*)&v_ring[slot][c4];
                const float uu = u_ring[slot][lr];
                float4 o;
                o.x = __expf(fmaf(cc.x, INV_EPS, uu + vv.x));
                o.y = __expf(fmaf(cc.y, INV_EPS, uu + vv.y));
                o.z = __expf(fmaf(cc.z, INV_EPS, uu + vv.z));
                o.w = __expf(fmaf(cc.w, INV_EPS, uu + vv.w));
                *(float4*)(out + e) = o;
            }
        }
    }
}

extern "C" void kernel_launch(void* const* d_in, const int* in_sizes, int n_in,
                              void* d_out, int out_size, void* d_ws, size_t ws_size,
                              hipStream_t stream) {
    const float* cost = (const float*)d_in[0];
    const float* src  = (const float*)d_in[1];
    const float* tgt  = (const float*)d_in[2];
    float* out = (float*)d_out;
    int*   ctrl = (int*)d_ws;
    (void)in_sizes; (void)n_in; (void)out_size;

    hipMemsetAsync(d_ws, 0, CTRL_INTS * sizeof(int), stream);

    const size_t need = (size_t)Q_OFF_BYTES + ((size_t)64 << 20);
    if (ws_size >= need) {
        uint* qbuf = (uint*)((char*)d_ws + Q_OFF_BYTES);
        sinkhorn_fused<1><<<dim3(NBLK), dim3(NTHR), 0, stream>>>(
            cost, src, tgt, out, ctrl, qbuf);
    } else {
        sinkhorn_fused<0><<<dim3(NBLK), dim3(NTHR), 0, stream>>>(
            cost, src, tgt, out, ctrl, nullptr);
    }
}